// Round 5
// baseline (77.750 us; speedup 1.0000x reference)
//
#include <hip/hip_runtime.h>

#define NRES  300
#define NTRJ  20
#define NBINS 34
#define PLANE (NTRJ * NRES * 3)   // 18000 floats per output tensor
#define NJT   19                  // j-tiles of 16
#define IC    6                   // i's per chunk
#define NCH   50                  // 300 / IC
#define GWT_FLOATS (300ull * 9 * 300 * 4)   // padded transposed gw: 12.96 MB

// ---- kernel 1: transpose gw[i][j][k] -> gwT[i][k4][j][c] (c = k%4, zero-pad k=34,35)
__global__ __launch_bounds__(256)
void transpose_gw(const float* __restrict__ gw, float* __restrict__ gwT) {
  __shared__ float t[64][35];
  const int bx = blockIdx.x;
  const int i  = bx / 5;
  const int jt = bx % 5;
  const int j0 = jt * 64;
  const int nj = (j0 + 64 <= NRES) ? 64 : (NRES - j0);
  const int F  = nj * NBINS;
  const float* src = gw + ((size_t)i * NRES + j0) * NBINS;
  for (int e = threadIdx.x; e < F; e += 256) t[e / NBINS][e % NBINS] = src[e];
  __syncthreads();
  const int jp = threadIdx.x >> 2;
  const int c  = threadIdx.x & 3;
  if (j0 + jp < NRES) {
#pragma unroll
    for (int k4 = 0; k4 < 9; ++k4) {
      int k = k4 * 4 + c;
      float v = (k < NBINS) ? t[jp][k] : 0.0f;
      gwT[(((size_t)i * 9 + k4) * NRES + j0 + jp) * 4 + c] = v;
    }
  }
}

// ---- kernel 2: forces. lane = (4 b x 16 j), 5 waves = 20 b, block = (jt, i-chunk)
template <bool USE_T>
__global__ __launch_bounds__(320)
void force_kernel(const float* __restrict__ cO,
                  const float* __restrict__ cCB,
                  const float* __restrict__ cH,
                  const float* __restrict__ g,      // gwT if USE_T else gw
                  const float* __restrict__ hmin,
                  const float* __restrict__ hmax,
                  float* __restrict__ out) {
  float* accO  = out + 2 * PLANE;
  float* accCB = out + 3 * PLANE;
  float* accH  = out + 4 * PLANE;

  const int tid  = threadIdx.x;
  const int wv   = tid >> 6;
  const int lane = tid & 63;
  const int bsub = lane >> 4;
  const int jsub = lane & 15;
  const int bx   = blockIdx.x;
  const int jt   = bx % NJT;
  const int ch   = bx / NJT;           // 0..NCH-1
  const int i0   = ch * IC;
  const int b    = wv * 4 + bsub;      // 0..19
  const int j    = jt * 16 + jsub;
  const bool jv  = (j < NRES);
  const int jc   = jv ? j : NRES - 1;

  const float* pj = cCB + ((size_t)(b * NRES + jc)) * 3;
  const float pjx = pj[0], pjy = pj[1], pjz = pj[2];
  const float* po = cO + ((size_t)(b * NRES + jc)) * 3;
  const float pox = po[0], poy = po[1], poz = po[2];

  float acx = 0.f, acy = 0.f, acz = 0.f;   // accs_CB[b,j]
  float aox = 0.f, aoy = 0.f, aoz = 0.f;   // accs_O [b,j]

  for (int ii = 0; ii < IC; ++ii) {
    const int i = i0 + ii;

    float w[36];
    if (USE_T) {
      // coalesced: 9 x float4, 16 consecutive j per 16B, bsub broadcast
      const float4* gp = (const float4*)g + (size_t)i * 9 * NRES + jc;
#pragma unroll
      for (int k4 = 0; k4 < 9; ++k4) {
        float4 v = gp[(size_t)k4 * NRES];
        w[4 * k4 + 0] = v.x; w[4 * k4 + 1] = v.y;
        w[4 * k4 + 2] = v.z; w[4 * k4 + 3] = v.w;
      }
    } else {
      const float2* gp = (const float2*)(g + ((size_t)i * NRES + jc) * NBINS);
#pragma unroll
      for (int k = 0; k < 17; ++k) { float2 v = gp[k]; w[2*k] = v.x; w[2*k+1] = v.y; }
      w[34] = 0.f; w[35] = 0.f;
    }

    const float hmn = hmin[i * NRES + jc];
    const float hmx = hmax[i * NRES + jc];

    // ---- CB distogram force: 3 x 12-bin gaussian recurrence chains ----
    const float* pi = cCB + ((size_t)(b * NRES + i)) * 3;
    float dx = pjx - pi[0], dy = pjy - pi[1], dz = pjz - pi[2];
    float d2 = fmaf(dx, dx, fmaf(dy, dy, dz * dz));
    d2 = fminf(fmaxf(d2, 0.01f), 1600.0f);     // clamp d to [0.1, 40]
    float rinv = __frsqrt_rn(d2);
    float d    = d2 * rinv;

    float dA = d - 3.75f, dB = d - 9.75f, dC = d - 15.75f;
    float gA = __expf(-0.32f * dA * dA), mA = __expf(fmaf(0.32f, dA, -0.08f));
    float gB = __expf(-0.32f * dB * dB), mB = __expf(fmaf(0.32f, dB, -0.08f));
    float gC = __expf(-0.32f * dC * dC), mC = __expf(fmaf(0.32f, dC, -0.08f));
    float s0 = 0.f, s1 = 0.f, s2 = 0.f;
#pragma unroll
    for (int k = 0; k < 12; ++k) {
      s0 = fmaf(w[k]      * dA, gA, s0); gA *= mA; mA *= 0.85214379f; dA -= 0.5f;
      s1 = fmaf(w[k + 12] * dB, gB, s1); gB *= mB; mB *= 0.85214379f; dB -= 0.5f;
      s2 = fmaf(w[k + 24] * dC, gC, s2); gC *= mC; mC *= 0.85214379f; dC -= 0.5f;
    }
    float cf = 76.8f * ((s0 + s1) + s2) * rinv;   // 150/sigma^3
    acx = fmaf(cf, dx, acx); acy = fmaf(cf, dy, acy); acz = fmaf(cf, dz, acz);

    // ---- HB min/max restraint (O_j - H_i) ----
    const float* ph = cH + ((size_t)(b * NRES + i)) * 3;
    float ex = pox - ph[0], ey = poy - ph[1], ez = poz - ph[2];
    float e2 = fmaf(ex, ex, fmaf(ey, ey, ez * ez));
    e2 = fminf(fmaxf(e2, 0.01f), 1600.0f);
    float rh = __frsqrt_rn(e2);
    float dh = e2 * rh;
    float vmin = fmaxf(hmn - dh, 0.0f);
    float vmax = fmaxf(dh - hmx, 0.0f);
    float fmn = 15.0f * vmin;                      // 3*5*v^1
    float fmx = (vmax > 0.0f) ? 5.0f * __powf(vmax, 0.75f) : 0.0f;
    float ff = (fmn - fmx) * rh;
    aox = fmaf(ff, ex, aox); aoy = fmaf(ff, ey, aoy); aoz = fmaf(ff, ez, aoz);

    // ---- fused accs_H[b,i]: reduce pair_hb over 16-lane jsub group ----
    float qx = jv ? ff * ex : 0.f;
    float qy = jv ? ff * ey : 0.f;
    float qz = jv ? ff * ez : 0.f;
#pragma unroll
    for (int m = 1; m < 16; m <<= 1) {
      qx += __shfl_xor(qx, m, 64);
      qy += __shfl_xor(qy, m, 64);
      qz += __shfl_xor(qz, m, 64);
    }
    if (jsub == 0) {
      const int hb = (b * NRES + i) * 3;
      atomicAdd(&accH[hb + 0], -qx);
      atomicAdd(&accH[hb + 1], -qy);
      atomicAdd(&accH[hb + 2], -qz);
    }
  }

  if (jv) {
    const int base = (b * NRES + j) * 3;
    atomicAdd(&accCB[base + 0], acx);
    atomicAdd(&accCB[base + 1], acy);
    atomicAdd(&accCB[base + 2], acz);
    atomicAdd(&accO[base + 0], aox);
    atomicAdd(&accO[base + 1], aoy);
    atomicAdd(&accO[base + 2], aoz);
  }
}

extern "C" void kernel_launch(void* const* d_in, const int* in_sizes, int n_in,
                              void* d_out, int out_size, void* d_ws, size_t ws_size,
                              hipStream_t stream) {
  // input order per setup_inputs(): N, C, O, CB, H, gaussian_weights, hb_min, hb_max
  const float* cO  = (const float*)d_in[2];
  const float* cCB = (const float*)d_in[3];
  const float* cH  = (const float*)d_in[4];
  const float* gw  = (const float*)d_in[5];
  const float* hmn = (const float*)d_in[6];
  const float* hmx = (const float*)d_in[7];
  float* out = (float*)d_out;

  // accs_N and accs_C are exactly zero (K_ANG_HB_GEN == 0); atomics need zeroed
  // accumulators -> zero the whole output every call (deterministic).
  hipMemsetAsync(out, 0, (size_t)out_size * sizeof(float), stream);

  if (ws_size >= GWT_FLOATS * sizeof(float)) {
    float* gwT = (float*)d_ws;
    transpose_gw<<<dim3(300 * 5), dim3(256), 0, stream>>>(gw, gwT);
    force_kernel<true><<<dim3(NJT * NCH), dim3(320), 0, stream>>>(
        cO, cCB, cH, gwT, hmn, hmx, out);
  } else {
    force_kernel<false><<<dim3(NJT * NCH), dim3(320), 0, stream>>>(
        cO, cCB, cH, gw, hmn, hmx, out);
  }
}

// Round 6
// 62.637 us; speedup vs baseline: 1.2413x; 1.2413x over previous
//
#include <hip/hip_runtime.h>

#define NRES  300
#define NTRJ  20
#define NBINS 34
#define PLANE (NTRJ * NRES * 3)      // 18000 floats per output tensor
#define NJT   5                      // j-tiles of 64 lanes
#define IC    4                      // i's per chunk
#define NCH   75                     // 300 / IC
#define NB    5                      // trajectories per lane (register-blocked)
#define PART_FLOATS (2ull * NCH * PLANE)   // CB + O partials: 10.8 MB

__device__ __forceinline__ float red64(float v) {
#pragma unroll
  for (int m = 1; m < 64; m <<= 1) v += __shfl_xor(v, m, 64);
  return v;
}

// lane = j (64 consecutive), wave = b-group of 5 trajectories, block = 4 waves
// (all 20 b) sharing (j-tile, i-chunk) -> gw rows hit L1 3 of 4 times.
// All accumulation in registers; CB/O partials -> plain stores to ws;
// accs_H -> wave shuffle-reduce + one lane-0 atomic per (b,i).
template <bool PART>
__global__ __launch_bounds__(256, 2)
void force_kernel(const float* __restrict__ cO,
                  const float* __restrict__ cCB,
                  const float* __restrict__ cH,
                  const float* __restrict__ gw,
                  const float* __restrict__ hmin,
                  const float* __restrict__ hmax,
                  float* __restrict__ out,
                  float* __restrict__ part) {
  float* accO  = out + 2 * PLANE;
  float* accCB = out + 3 * PLANE;
  float* accH  = out + 4 * PLANE;

  const int lane = threadIdx.x & 63;
  // wave-uniform b-group as an SGPR so per-(b,i) coord loads become scalar
  const int bg   = __builtin_amdgcn_readfirstlane(threadIdx.x >> 6);  // 0..3
  const int b0   = bg * NB;
  const int bx   = blockIdx.x;
  const int jt   = bx % NJT;
  const int ch   = bx / NJT;          // 0..NCH-1
  const int i0   = ch * IC;
  const int j    = jt * 64 + lane;
  const bool jv  = (j < NRES);
  const int jc   = jv ? j : NRES - 1;

  // this lane's j-side coordinates for its 5 trajectories (fixed all kernel)
  float pjx[NB], pjy[NB], pjz[NB], pox[NB], poy[NB], poz[NB];
  float acx[NB] = {}, acy[NB] = {}, acz[NB] = {};   // accs_CB[b,j] partials
  float aox[NB] = {}, aoy[NB] = {}, aoz[NB] = {};   // accs_O [b,j] partials
#pragma unroll
  for (int q = 0; q < NB; ++q) {
    const float* p = cCB + ((size_t)((b0 + q) * NRES + jc)) * 3;
    pjx[q] = p[0]; pjy[q] = p[1]; pjz[q] = p[2];
    const float* o = cO + ((size_t)((b0 + q) * NRES + jc)) * 3;
    pox[q] = o[0]; poy[q] = o[1]; poz[q] = o[2];
  }

#pragma unroll
  for (int ii = 0; ii < IC; ++ii) {
    const int i = i0 + ii;

    // gw row for (i, lane's j): 17 x b64; 8.7 KB wave tile lives in L1
    float w[36];
    const float2* gp = (const float2*)(gw + ((size_t)i * NRES + jc) * NBINS);
#pragma unroll
    for (int k = 0; k < 17; ++k) { float2 v = gp[k]; w[2*k] = v.x; w[2*k+1] = v.y; }
    w[34] = 0.f; w[35] = 0.f;
    const float hmn = hmin[i * NRES + jc];
    const float hmx = hmax[i * NRES + jc];

#pragma unroll
    for (int q = 0; q < NB; ++q) {
      const int b = b0 + q;
      // wave-uniform i-side coords (SGPR address -> scalar loads)
      const float* pi = cCB + ((size_t)(b * NRES + i)) * 3;
      const float* ph = cH  + ((size_t)(b * NRES + i)) * 3;

      // ---- CB distogram force: 3 x 12-bin gaussian recurrence ----
      float dx = pjx[q] - pi[0], dy = pjy[q] - pi[1], dz = pjz[q] - pi[2];
      float d2 = fmaf(dx, dx, fmaf(dy, dy, dz * dz));
      d2 = fminf(fmaxf(d2, 0.01f), 1600.0f);      // d in [0.1, 40]
      float rinv = __frsqrt_rn(d2);
      float d    = d2 * rinv;

      float dA = d - 3.75f, dB = d - 9.75f, dC = d - 15.75f;
      float gA = __expf(-0.32f * dA * dA), mA = __expf(fmaf(0.32f, dA, -0.08f));
      float gB = __expf(-0.32f * dB * dB), mB = __expf(fmaf(0.32f, dB, -0.08f));
      float gC = __expf(-0.32f * dC * dC), mC = __expf(fmaf(0.32f, dC, -0.08f));
      float s0 = 0.f, s1 = 0.f, s2 = 0.f;
#pragma unroll
      for (int k = 0; k < 12; ++k) {
        s0 = fmaf(w[k]      * dA, gA, s0); gA *= mA; mA *= 0.85214379f; dA -= 0.5f;
        s1 = fmaf(w[k + 12] * dB, gB, s1); gB *= mB; mB *= 0.85214379f; dB -= 0.5f;
        s2 = fmaf(w[k + 24] * dC, gC, s2); gC *= mC; mC *= 0.85214379f; dC -= 0.5f;
      }
      float cf = 76.8f * ((s0 + s1) + s2) * rinv;  // 150 / sigma^3
      acx[q] = fmaf(cf, dx, acx[q]);
      acy[q] = fmaf(cf, dy, acy[q]);
      acz[q] = fmaf(cf, dz, acz[q]);

      // ---- HB min/max restraint (O_j - H_i) ----
      float ex = pox[q] - ph[0], ey = poy[q] - ph[1], ez = poz[q] - ph[2];
      float e2 = fmaf(ex, ex, fmaf(ey, ey, ez * ez));
      e2 = fminf(fmaxf(e2, 0.01f), 1600.0f);
      float rh = __frsqrt_rn(e2);
      float dh = e2 * rh;
      float vmin = fmaxf(hmn - dh, 0.0f);
      float vmax = fmaxf(dh - hmx, 0.0f);
      float fmn = 15.0f * vmin;                    // 3*5*v^1
      float fmx = (vmax > 0.0f) ? 5.0f * __powf(vmax, 0.75f) : 0.0f;
      float ff = (fmn - fmx) * rh;
      aox[q] = fmaf(ff, ex, aox[q]);
      aoy[q] = fmaf(ff, ey, aoy[q]);
      aoz[q] = fmaf(ff, ez, aoz[q]);

      // ---- accs_H[b,i] = -sum_j pair_hb : 64-lane reduce, 1 atomic ----
      float qx = jv ? ff * ex : 0.f;
      float qy = jv ? ff * ey : 0.f;
      float qz = jv ? ff * ez : 0.f;
      qx = red64(qx); qy = red64(qy); qz = red64(qz);
      if (lane == 0) {
        const int hb = (b * NRES + i) * 3;
        atomicAdd(&accH[hb + 0], -qx);
        atomicAdd(&accH[hb + 1], -qy);
        atomicAdd(&accH[hb + 2], -qz);
      }
    }
  }

  if (jv) {
    if constexpr (PART) {
      // plain coalesced stores of per-chunk partials (no atomics)
      float* pc = part + (size_t)ch * PLANE;
      float* po2 = part + (size_t)(NCH + ch) * PLANE;
#pragma unroll
      for (int q = 0; q < NB; ++q) {
        const int base = ((b0 + q) * NRES + j) * 3;
        pc[base + 0]  = acx[q]; pc[base + 1]  = acy[q]; pc[base + 2]  = acz[q];
        po2[base + 0] = aox[q]; po2[base + 1] = aoy[q]; po2[base + 2] = aoz[q];
      }
    } else {
#pragma unroll
      for (int q = 0; q < NB; ++q) {
        const int base = ((b0 + q) * NRES + j) * 3;
        atomicAdd(&accCB[base + 0], acx[q]);
        atomicAdd(&accCB[base + 1], acy[q]);
        atomicAdd(&accCB[base + 2], acz[q]);
        atomicAdd(&accO[base + 0], aox[q]);
        atomicAdd(&accO[base + 1], aoy[q]);
        atomicAdd(&accO[base + 2], aoz[q]);
      }
    }
  }
}

// out[b,j,c] = sum over 75 chunk planes; coalesced stride-PLANE reads
__global__ __launch_bounds__(256)
void reduce_part(const float* __restrict__ part, float* __restrict__ out) {
  const int t = blockIdx.x * 256 + threadIdx.x;
  if (t >= PLANE) return;
  float scb = 0.f, so = 0.f;
  const float* pc = part + t;
  const float* po = part + (size_t)NCH * PLANE + t;
#pragma unroll 5
  for (int ch = 0; ch < NCH; ++ch) {
    scb += pc[(size_t)ch * PLANE];
    so  += po[(size_t)ch * PLANE];
  }
  out[3 * PLANE + t] = scb;   // accs_CB
  out[2 * PLANE + t] = so;    // accs_O
}

extern "C" void kernel_launch(void* const* d_in, const int* in_sizes, int n_in,
                              void* d_out, int out_size, void* d_ws, size_t ws_size,
                              hipStream_t stream) {
  // input order per setup_inputs(): N, C, O, CB, H, gaussian_weights, hb_min, hb_max
  const float* cO  = (const float*)d_in[2];
  const float* cCB = (const float*)d_in[3];
  const float* cH  = (const float*)d_in[4];
  const float* gw  = (const float*)d_in[5];
  const float* hmn = (const float*)d_in[6];
  const float* hmx = (const float*)d_in[7];
  float* out = (float*)d_out;

  // accs_N and accs_C are exactly zero (K_ANG_HB_GEN == 0); H atomics need a
  // zeroed plane -> zero the whole output every call (deterministic).
  hipMemsetAsync(out, 0, (size_t)out_size * sizeof(float), stream);

  if (ws_size >= PART_FLOATS * sizeof(float)) {
    float* part = (float*)d_ws;
    force_kernel<true><<<dim3(NJT * NCH), dim3(256), 0, stream>>>(
        cO, cCB, cH, gw, hmn, hmx, out, part);
    reduce_part<<<dim3((PLANE + 255) / 256), dim3(256), 0, stream>>>(part, out);
  } else {
    force_kernel<false><<<dim3(NJT * NCH), dim3(256), 0, stream>>>(
        cO, cCB, cH, gw, hmn, hmx, out, nullptr);
  }
}